// Round 3
// baseline (924.355 us; speedup 1.0000x reference)
//
#include <hip/hip_runtime.h>
#include <hip/hip_bf16.h>

#define NNODES 50000
#define NEDGES 1600000
#define NBIN   782      // ceil(50000/64) destination bins, 64 nodes each
#define SCAP   512      // per-(xcd,bin) sub-buffer capacity; mean ~256, sigma ~16
#define OVFCAP 65536    // overflow list entries (expected use: 0)
#define BCHUNK 2000
#define NBBLK  800      // NBBLK * BCHUNK == NEDGES

__device__ __forceinline__ float bf2f(unsigned short u) {
    union { unsigned int i; float f; } x; x.i = ((unsigned int)u) << 16; return x.f;
}

// ---------------------------------------------------------------------------
// 1) Single-read LDS-staged binning with per-XCD sub-buffers (round-2 design,
//    unchanged: ~30 us, near latency floor). Packs row | (c&63)<<16 | bin<<22.
__global__ __launch_bounds__(256) void k_bin(const int* __restrict__ edges,
                                             int* __restrict__ bincur,
                                             int* __restrict__ ovfcnt,
                                             int* __restrict__ ovf,
                                             int* __restrict__ binned) {
    __shared__ int pk[BCHUNK];
    __shared__ int hist[NBIN];
    __shared__ int gbase[NBIN];
    __shared__ int lcnt[NBIN];
    int t = threadIdx.x;
    int e0 = blockIdx.x * BCHUNK;
    unsigned xcd;
    asm volatile("s_getreg_b32 %0, hwreg(HW_REG_XCC_ID)" : "=s"(xcd));
    xcd &= 7;
    for (int i = t; i < NBIN; i += 256) { hist[i] = 0; lcnt[i] = 0; }
    __syncthreads();
    for (int i = t * 4; i < BCHUNK; i += 1024) {
        int4 r4 = *(const int4*)&edges[e0 + i];
        int4 c4 = *(const int4*)&edges[NEDGES + e0 + i];
        int b0 = c4.x >> 6, b1 = c4.y >> 6, b2 = c4.z >> 6, b3 = c4.w >> 6;
        pk[i + 0] = r4.x | ((c4.x & 63) << 16) | (b0 << 22);
        pk[i + 1] = r4.y | ((c4.y & 63) << 16) | (b1 << 22);
        pk[i + 2] = r4.z | ((c4.z & 63) << 16) | (b2 << 22);
        pk[i + 3] = r4.w | ((c4.w & 63) << 16) | (b3 << 22);
        atomicAdd(&hist[b0], 1);
        atomicAdd(&hist[b1], 1);
        atomicAdd(&hist[b2], 1);
        atomicAdd(&hist[b3], 1);
    }
    __syncthreads();
    for (int i = t; i < NBIN; i += 256) {
        int h = hist[i];
        gbase[i] = (h > 0) ? atomicAdd(&bincur[xcd * NBIN + i], h) : 0;
    }
    __syncthreads();
    for (int i = t; i < BCHUNK; i += 256) {
        int v = pk[i];
        int bin = ((unsigned)v) >> 22;
        int p = gbase[bin] + atomicAdd(&lcnt[bin], 1);
        if (p < SCAP) {
            binned[(xcd * NBIN + bin) * SCAP + p] = v & 0x3FFFFF;
        } else {
            int op = atomicAdd(ovfcnt, 1);
            if (op < OVFCAP) ovf[op] = v;   // keep bin bits for filtering
        }
    }
}

// ---------------------------------------------------------------------------
// 2) Per-bin degree histogram -> dinv + pre-scaled bf16 x0s rows.
//    (The old counting-sort placement pass + csr are gone: k_agg consumes
//    the unsorted binned entries directly.)
__global__ __launch_bounds__(256) void k_prep(const int* __restrict__ bincur,
                                              const int* __restrict__ binned,
                                              const int* __restrict__ ovfcnt,
                                              const int* __restrict__ ovf,
                                              const float* __restrict__ x,
                                              float* __restrict__ dinv,
                                              unsigned short* __restrict__ x0s) {
    __shared__ int h[64];
    __shared__ float dv[64];
    int t = threadIdx.x, bin = blockIdx.x;
    int wave = t >> 6, lane = t & 63;
    if (t < 64) h[t] = 0;
    __syncthreads();
    for (int s = 0; s < 8; ++s) {
        int len = min(bincur[s * NBIN + bin], SCAP);
        const int* __restrict__ bb = binned + (s * NBIN + bin) * SCAP;
        for (int e = t; e < len; e += 256)
            atomicAdd(&h[(bb[e] >> 16) & 63], 1);
    }
    int novf = ovfcnt[0];
    for (int e = t; e < novf; e += 256) {
        int v = ovf[e];
        if (((unsigned)v >> 22) == (unsigned)bin) atomicAdd(&h[(v >> 16) & 63], 1);
    }
    __syncthreads();
    if (t < 64) {
        float dc = rsqrtf((float)(h[t] + 1));
        dv[t] = dc;
        int n = bin * 64 + t;
        if (n < NNODES) dinv[n] = dc;
    }
    __syncthreads();
    for (int i = wave; i < 64; i += 4) {
        int n = bin * 64 + i;
        if (n < NNODES) {
            __hip_bfloat16 v = __float2bfloat16(x[n * 256 + lane] * dv[i]);
            x0s[n * 64 + lane] = *(unsigned short*)&v;
        }
    }
}

// ---------------------------------------------------------------------------
// 3) Fused per-bin aggregate + GEMM. acc[64 nodes][64 feats] fp32 in LDS
//    (16 KB). Waves stream unsorted binned entries: broadcast (r,c), all
//    lanes load x0s[r] (128B coalesced) and ds_add_f32 into acc[c][lane]
//    (fire-and-forget -> no accumulator dependency chain, deep pipelining;
//    lane->bank mapping 2-way = free). Tail: scale by dinv, W cols to regs
//    (loaded after the barrier so gather-phase VGPR pressure stays low),
//    64x64 per-thread dot products reading acc via broadcast ds_read_b128,
//    relu + dual nontemporal store. Eliminates csr (12.8 MB rt) and agg
//    (25.6 MB rt) plus two launches.
__global__ __launch_bounds__(256) void k_agg(const int* __restrict__ bincur,
                                             const int* __restrict__ binned,
                                             const int* __restrict__ ovfcnt,
                                             const int* __restrict__ ovf,
                                             const unsigned short* __restrict__ x0s,
                                             const float* __restrict__ dinv,
                                             const float* __restrict__ W,
                                             const float* __restrict__ b,
                                             float* __restrict__ out0,
                                             float* __restrict__ out1) {
    __shared__ float acc[64 * 64];
    int t = threadIdx.x, bin = blockIdx.x;
    int wave = t >> 6, lane = t & 63;
    int n0 = bin * 64;
    // init with self-loop rows (pre-scaled); invalid rows -> 0
    for (int i = wave; i < 64; i += 4) {
        int n = n0 + i;
        acc[i * 64 + lane] = (n < NNODES) ? bf2f(x0s[n * 64 + lane]) : 0.0f;
    }
    __syncthreads();
    // edge accumulation over the 8 XCD segments
    for (int s = 0; s < 8; ++s) {
        int len = min(bincur[s * NBIN + bin], SCAP);
        const int* __restrict__ bb = binned + (s * NBIN + bin) * SCAP;
        for (int base = wave * 64; base < len; base += 256) {
            int m = min(len - base, 64);
            int v = (lane < m) ? bb[base + lane] : 0;
            int j = 0;
            for (; j + 8 <= m; j += 8) {
                int v0 = __shfl(v, j + 0), v1 = __shfl(v, j + 1);
                int v2 = __shfl(v, j + 2), v3 = __shfl(v, j + 3);
                int v4 = __shfl(v, j + 4), v5 = __shfl(v, j + 5);
                int v6 = __shfl(v, j + 6), v7 = __shfl(v, j + 7);
                float f0 = bf2f(x0s[(v0 & 0xFFFF) * 64 + lane]);
                float f1 = bf2f(x0s[(v1 & 0xFFFF) * 64 + lane]);
                float f2 = bf2f(x0s[(v2 & 0xFFFF) * 64 + lane]);
                float f3 = bf2f(x0s[(v3 & 0xFFFF) * 64 + lane]);
                float f4 = bf2f(x0s[(v4 & 0xFFFF) * 64 + lane]);
                float f5 = bf2f(x0s[(v5 & 0xFFFF) * 64 + lane]);
                float f6 = bf2f(x0s[(v6 & 0xFFFF) * 64 + lane]);
                float f7 = bf2f(x0s[(v7 & 0xFFFF) * 64 + lane]);
                atomicAdd(&acc[((v0 >> 16) & 63) * 64 + lane], f0);
                atomicAdd(&acc[((v1 >> 16) & 63) * 64 + lane], f1);
                atomicAdd(&acc[((v2 >> 16) & 63) * 64 + lane], f2);
                atomicAdd(&acc[((v3 >> 16) & 63) * 64 + lane], f3);
                atomicAdd(&acc[((v4 >> 16) & 63) * 64 + lane], f4);
                atomicAdd(&acc[((v5 >> 16) & 63) * 64 + lane], f5);
                atomicAdd(&acc[((v6 >> 16) & 63) * 64 + lane], f6);
                atomicAdd(&acc[((v7 >> 16) & 63) * 64 + lane], f7);
            }
            for (; j < m; ++j) {
                int vv = __shfl(v, j);
                float f = bf2f(x0s[(vv & 0xFFFF) * 64 + lane]);
                atomicAdd(&acc[((vv >> 16) & 63) * 64 + lane], f);
            }
        }
    }
    // overflow entries (expected none)
    int novf = ovfcnt[0];
    for (int base = wave * 64; base < novf; base += 256) {
        int m = min(novf - base, 64);
        int v = (lane < m) ? ovf[base + lane] : 0;
        for (int j = 0; j < m; ++j) {
            int vv = __shfl(v, j);
            if (((unsigned)vv >> 22) == (unsigned)bin) {
                float f = bf2f(x0s[(vv & 0xFFFF) * 64 + lane]);
                atomicAdd(&acc[((vv >> 16) & 63) * 64 + lane], f);
            }
        }
    }
    __syncthreads();
    // scale rows by dinv[c]
    for (int i = wave; i < 64; i += 4) {
        int n = n0 + i;
        float dc = (n < NNODES) ? dinv[n] : 0.0f;
        acc[i * 64 + lane] *= dc;
    }
    __syncthreads();
    // GEMM tail: thread t = (h = wave, o = lane)
    float wreg[64];
    #pragma unroll
    for (int f = 0; f < 64; ++f) wreg[f] = W[wave * 4096 + f * 64 + lane];
    float bias = b[t];
    int nmax = min(64, NNODES - n0);
    for (int i = 0; i < nmax; ++i) {
        const float4* __restrict__ av = (const float4*)&acc[i * 64];
        float s0 = bias, s1 = 0.0f, s2 = 0.0f, s3 = 0.0f;
        #pragma unroll
        for (int f4 = 0; f4 < 16; ++f4) {
            float4 a = av[f4];
            s0 = fmaf(a.x, wreg[4 * f4 + 0], s0);
            s1 = fmaf(a.y, wreg[4 * f4 + 1], s1);
            s2 = fmaf(a.z, wreg[4 * f4 + 2], s2);
            s3 = fmaf(a.w, wreg[4 * f4 + 3], s3);
        }
        float vv = fmaxf((s0 + s1) + (s2 + s3), 0.0f);
        int n = n0 + i;
        __builtin_nontemporal_store(vv, &out0[n * 256 + t]);
        __builtin_nontemporal_store(vv, &out1[n * 256 + t]);
    }
}

// ---------------------------------------------------------------------------

extern "C" void kernel_launch(void* const* d_in, const int* in_sizes, int n_in,
                              void* d_out, int out_size, void* d_ws, size_t ws_size,
                              hipStream_t stream) {
    const float* x     = (const float*)d_in[0];   // (50000, 256) f32
    const int*   edges = (const int*)d_in[1];     // (2, 1600000) int32
    const float* W     = (const float*)d_in[2];   // (4, 64, 64) f32
    const float* b     = (const float*)d_in[3];   // (4, 64) f32

    float* out0 = (float*)d_out;                   // x_cat (50000,256)
    float* out1 = out0 + (size_t)NNODES * 256;     // heads (50000,4,64) — same values

    // workspace layout
    char* ws = (char*)d_ws;
    int*            bincur = (int*)(ws + 0);              //  25,024 B (8 XCD x 782 bins)
    int*            ovfcnt = (int*)(ws + 25024);          //       4 B
    int*            ovf    = (int*)(ws + 25600);          // 262,144 B
    float*          dinv   = (float*)(ws + 287744);       // 200,000 B
    unsigned short* x0s    = (unsigned short*)(ws + 488448);   // 6,400,000 B
    int*            binned = (int*)(ws + 6888448);        // 12,812,288 B (8 x 782 x 512)
    // total ~19.7 MB

    hipMemsetAsync(ws, 0, 25028, stream);   // bincur + ovfcnt
    k_bin <<<NBBLK, 256, 0, stream>>>(edges, bincur, ovfcnt, ovf, binned);
    k_prep<<<NBIN, 256, 0, stream>>>(bincur, binned, ovfcnt, ovf, x, dinv, x0s);
    k_agg <<<NBIN, 256, 0, stream>>>(bincur, binned, ovfcnt, ovf, x0s, dinv, W, b, out0, out1);
}

// Round 4
// 337.698 us; speedup vs baseline: 2.7372x; 2.7372x over previous
//
#include <hip/hip_runtime.h>
#include <hip/hip_bf16.h>

#define NNODES 50000
#define NEDGES 1600000
#define SCAPN  16       // per-(xcd,node) list capacity; per-cell mean 4, Poisson tail ~1e-7
#define OVFCAP 65536    // overflow list entries (expected use: 0)

__device__ __forceinline__ float bf2f(unsigned short u) {
    union { unsigned int i; float f; } x; x.i = ((unsigned int)u) << 16; return x.f;
}

// ---------------------------------------------------------------------------
// 1) Direct padded CSR build, full TLP (1563 blocks). One pass over edges:
//    p = atomicAdd(curnx[xcd][c]); csrx[xcd][c][p] = r. Counters and list
//    lines are only touched by blocks on their own XCD (round-2 lesson: no
//    cross-XCD line ping-pong). Degrees fall out as the final counter values.
//    No bins, no histogram, no sort, no prefix scan.
__global__ __launch_bounds__(256) void k_place(const int* __restrict__ edges,
                                               int* __restrict__ curnx,
                                               int* __restrict__ ovfcnt,
                                               int* __restrict__ ovf,
                                               int* __restrict__ csrx) {
    int gid = blockIdx.x * 256 + threadIdx.x;
    if (gid >= NEDGES / 4) return;
    unsigned xcd;
    asm volatile("s_getreg_b32 %0, hwreg(HW_REG_XCC_ID)" : "=s"(xcd));
    xcd &= 7;
    int4 r4 = *(const int4*)&edges[gid * 4];
    int4 c4 = *(const int4*)&edges[NEDGES + gid * 4];
    int rr[4] = { r4.x, r4.y, r4.z, r4.w };
    int cc[4] = { c4.x, c4.y, c4.z, c4.w };
    #pragma unroll
    for (int j = 0; j < 4; ++j) {
        int c = cc[j];
        int p = atomicAdd(&curnx[xcd * NNODES + c], 1);
        if (p < SCAPN) {
            csrx[(xcd * NNODES + c) * SCAPN + p] = rr[j];
        } else {
            int op = atomicAdd(ovfcnt, 1);
            if (op < OVFCAP) ovf[op] = gid * 4 + j;   // store edge id
        }
    }
}

// ---------------------------------------------------------------------------
// 2) Full-TLP prep (50K waves, wave = node): deg = sum of 8 XCD counters
//    (uncapped -> exact normalization even if an edge overflowed), dinv,
//    pre-scaled bf16 x0s row.
__global__ __launch_bounds__(256) void k_prep(const int* __restrict__ curnx,
                                              const float* __restrict__ x,
                                              float* __restrict__ dinv,
                                              unsigned short* __restrict__ x0s) {
    int t = threadIdx.x, lane = t & 63, w = t >> 6;
    int n = blockIdx.x * 4 + w;            // 12500 * 4 = 50000 exactly
    int v = (lane < 8) ? curnx[lane * NNODES + n] : 0;
    int deg = v;
    #pragma unroll
    for (int d = 1; d < 64; d <<= 1) deg += __shfl_xor(deg, d);
    float dc = rsqrtf((float)(deg + 1));
    if (lane == 0) dinv[n] = dc;
    __hip_bfloat16 bv = __float2bfloat16(x[n * 256 + lane] * dc);
    x0s[n * 64 + lane] = *(unsigned short*)&bv;
}

// ---------------------------------------------------------------------------
// 3) Fused gather + GEMM at round-2 gather geometry (wave = node, 50K waves,
//    register accumulate, lane = feature). Each wave assembles its node's
//    indices from the 8 XCD segments with ONE per-lane mapped gather load
//    (lane -> (segment, offset) via an 8-step uniform scan), then the proven
//    8-wide shfl-broadcast batch loop. Rows hand off to the GEMM tail through
//    1 KB LDS -> the 25.6 MB agg round-trip and one launch are gone.
__global__ __launch_bounds__(256) void k_gq(const int* __restrict__ edges,
                                            const int* __restrict__ curnx,
                                            const int* __restrict__ ovfcnt,
                                            const int* __restrict__ ovf,
                                            const int* __restrict__ csrx,
                                            const unsigned short* __restrict__ x0s,
                                            const float* __restrict__ dinv,
                                            const float* __restrict__ W,
                                            const float* __restrict__ b,
                                            float* __restrict__ out0,
                                            float* __restrict__ out1) {
    __shared__ float rows[4][64];
    int t = threadIdx.x, lane = t & 63, w = t >> 6;
    int n = blockIdx.x * 4 + w;            // 12500 * 4 = 50000 exactly
    // per-segment capped lengths -> total cnt (wave-uniform)
    int cl = 0;
    if (lane < 8) cl = min(curnx[lane * NNODES + n], SCAPN);
    int cnt = cl;
    #pragma unroll
    for (int d = 1; d < 64; d <<= 1) cnt += __shfl_xor(cnt, d);
    float acc0 = bf2f(x0s[n * 64 + lane]);   // self-loop (pre-scaled)
    float acc1 = 0.0f;
    for (int base = 0; base < cnt; base += 64) {
        int m = min(cnt - base, 64);
        // map target index (base+lane) -> (segment s, offset) and gather-load
        int ti = base + lane;
        int addr = 0, pre = 0, have = 0;
        #pragma unroll
        for (int s = 0; s < 8; ++s) {
            int ls = __shfl(cl, s);
            if (ti >= pre && ti < pre + ls) {
                addr = (s * NNODES + n) * SCAPN + (ti - pre);
                have = 1;
            }
            pre += ls;
        }
        int idx = (lane < m && have) ? csrx[addr] : 0;
        int j = 0;
        for (; j + 8 <= m; j += 8) {
            int r0 = __shfl(idx, j + 0), r1 = __shfl(idx, j + 1);
            int r2 = __shfl(idx, j + 2), r3 = __shfl(idx, j + 3);
            int r4 = __shfl(idx, j + 4), r5 = __shfl(idx, j + 5);
            int r6 = __shfl(idx, j + 6), r7 = __shfl(idx, j + 7);
            float f0 = bf2f(x0s[r0 * 64 + lane]);
            float f1 = bf2f(x0s[r1 * 64 + lane]);
            float f2 = bf2f(x0s[r2 * 64 + lane]);
            float f3 = bf2f(x0s[r3 * 64 + lane]);
            float f4 = bf2f(x0s[r4 * 64 + lane]);
            float f5 = bf2f(x0s[r5 * 64 + lane]);
            float f6 = bf2f(x0s[r6 * 64 + lane]);
            float f7 = bf2f(x0s[r7 * 64 + lane]);
            acc0 += (f0 + f1) + (f2 + f3);
            acc1 += (f4 + f5) + (f6 + f7);
        }
        for (; j < m; ++j) {
            int r = __shfl(idx, j);
            acc0 += bf2f(x0s[r * 64 + lane]);
        }
    }
    // overflow drain (expected empty)
    int novf = min(ovfcnt[0], OVFCAP);
    for (int e = 0; e < novf; ++e) {
        int ei = ovf[e];
        if (edges[NEDGES + ei] == n) acc0 += bf2f(x0s[edges[ei] * 64 + lane]);
    }
    rows[w][lane] = (acc0 + acc1) * dinv[n];
    __syncthreads();
    // GEMM tail: thread t = (h = t>>6, o = t&63), 4 nodes from LDS
    int h = t >> 6, o = t & 63;
    float wreg[64];
    #pragma unroll
    for (int f = 0; f < 64; ++f) wreg[f] = W[h * 4096 + f * 64 + o];
    float bias = b[t];
    #pragma unroll
    for (int i = 0; i < 4; ++i) {
        const float4* __restrict__ av = (const float4*)&rows[i][0];
        float s0 = bias, s1 = 0.0f, s2 = 0.0f, s3 = 0.0f;
        #pragma unroll
        for (int f4 = 0; f4 < 16; ++f4) {
            float4 a = av[f4];
            s0 = fmaf(a.x, wreg[4 * f4 + 0], s0);
            s1 = fmaf(a.y, wreg[4 * f4 + 1], s1);
            s2 = fmaf(a.z, wreg[4 * f4 + 2], s2);
            s3 = fmaf(a.w, wreg[4 * f4 + 3], s3);
        }
        float vv = fmaxf((s0 + s1) + (s2 + s3), 0.0f);
        int nn = blockIdx.x * 4 + i;
        __builtin_nontemporal_store(vv, &out0[nn * 256 + t]);
        __builtin_nontemporal_store(vv, &out1[nn * 256 + t]);
    }
}

// ---------------------------------------------------------------------------

extern "C" void kernel_launch(void* const* d_in, const int* in_sizes, int n_in,
                              void* d_out, int out_size, void* d_ws, size_t ws_size,
                              hipStream_t stream) {
    const float* x     = (const float*)d_in[0];   // (50000, 256) f32
    const int*   edges = (const int*)d_in[1];     // (2, 1600000) int32
    const float* W     = (const float*)d_in[2];   // (4, 64, 64) f32
    const float* b     = (const float*)d_in[3];   // (4, 64) f32

    float* out0 = (float*)d_out;                   // x_cat (50000,256)
    float* out1 = out0 + (size_t)NNODES * 256;     // heads (50000,4,64) — same values

    // workspace layout (512B-aligned sections)
    char* ws = (char*)d_ws;
    int*            curnx  = (int*)(ws + 0);              //  1,600,000 B (8 XCD x 50000)
    int*            ovfcnt = (int*)(ws + 1600000);        //          4 B
    int*            ovf    = (int*)(ws + 1600512);        //    262,144 B
    float*          dinv   = (float*)(ws + 1862656);      //    200,000 B
    unsigned short* x0s    = (unsigned short*)(ws + 2063360);   // 6,400,000 B
    int*            csrx   = (int*)(ws + 8463360);        // 25,600,000 B (8 x 50000 x 16)
    // total ~34.1 MB

    hipMemsetAsync(ws, 0, 1600004, stream);   // curnx + ovfcnt
    k_place<<<(NEDGES / 4 + 255) / 256, 256, 0, stream>>>(edges, curnx, ovfcnt, ovf, csrx);
    k_prep <<<NNODES / 4, 256, 0, stream>>>(curnx, x, dinv, x0s);
    k_gq   <<<NNODES / 4, 256, 0, stream>>>(edges, curnx, ovfcnt, ovf, csrx, x0s, dinv, W, b, out0, out1);
}

// Round 5
// 316.107 us; speedup vs baseline: 2.9242x; 1.0683x over previous
//
#include <hip/hip_runtime.h>
#include <hip/hip_bf16.h>

#define NNODES 50000
#define NEDGES 1600000
#define NBIN   782      // ceil(50000/64) destination bins of 64 nodes
#define SCAP   512      // per-(xcd,bin) segment capacity; mean 256, sigma 16
#define SCAPN  20       // per-(segment,node) cell capacity; mean 4, P(>20)~1e-8
#define OVFCAP 65536    // overflow list (expected ~0 entries)
#define BCHUNK 2000
#define NBBLK  800      // NBBLK * BCHUNK == NEDGES

__device__ __forceinline__ float bf2f(unsigned short u) {
    union { unsigned int i; float f; } x; x.i = ((unsigned int)u) << 16; return x.f;
}

// ---------------------------------------------------------------------------
// 1) Round-2 binning (proven ~30 us) + fire-and-forget per-(xcd,node) degree
//    atomics in the success branch (non-returning, XCD-local 200 KB in L2).
//    Packs row | (c&63)<<16 | bin<<22.
__global__ __launch_bounds__(256) void k_bin(const int* __restrict__ edges,
                                             int* __restrict__ bincur,
                                             int* __restrict__ curnx,
                                             int* __restrict__ ovfcnt,
                                             int* __restrict__ ovf,
                                             int* __restrict__ binned) {
    __shared__ int pk[BCHUNK];
    __shared__ int hist[NBIN];
    __shared__ int gbase[NBIN];
    __shared__ int lcnt[NBIN];
    int t = threadIdx.x;
    int e0 = blockIdx.x * BCHUNK;
    unsigned xcd;
    asm volatile("s_getreg_b32 %0, hwreg(HW_REG_XCC_ID)" : "=s"(xcd));
    xcd &= 7;
    for (int i = t; i < NBIN; i += 256) { hist[i] = 0; lcnt[i] = 0; }
    __syncthreads();
    for (int i = t * 4; i < BCHUNK; i += 1024) {
        int4 r4 = *(const int4*)&edges[e0 + i];
        int4 c4 = *(const int4*)&edges[NEDGES + e0 + i];
        int b0 = c4.x >> 6, b1 = c4.y >> 6, b2 = c4.z >> 6, b3 = c4.w >> 6;
        pk[i + 0] = r4.x | ((c4.x & 63) << 16) | (b0 << 22);
        pk[i + 1] = r4.y | ((c4.y & 63) << 16) | (b1 << 22);
        pk[i + 2] = r4.z | ((c4.z & 63) << 16) | (b2 << 22);
        pk[i + 3] = r4.w | ((c4.w & 63) << 16) | (b3 << 22);
        atomicAdd(&hist[b0], 1);
        atomicAdd(&hist[b1], 1);
        atomicAdd(&hist[b2], 1);
        atomicAdd(&hist[b3], 1);
    }
    __syncthreads();
    for (int i = t; i < NBIN; i += 256) {
        int h = hist[i];
        gbase[i] = (h > 0) ? atomicAdd(&bincur[xcd * NBIN + i], h) : 0;
    }
    __syncthreads();
    for (int i = t; i < BCHUNK; i += 256) {
        int v = pk[i];
        int bin = ((unsigned)v) >> 22;
        int p = gbase[bin] + atomicAdd(&lcnt[bin], 1);
        if (p < SCAP) {
            binned[(xcd * NBIN + bin) * SCAP + p] = v & 0x3FFFFF;
            int c = (bin << 6) | ((v >> 16) & 63);
            atomicAdd(&curnx[xcd * NNODES + c], 1);   // non-returning, XCD-local
        } else {
            int op = atomicAdd(ovfcnt, 1);
            if (op < OVFCAP) ovf[op] = v;   // not counted in curnx; k_prep fixes deg
        }
    }
}

// ---------------------------------------------------------------------------
// 2) Prep (runs BEFORE k_seg so ovf holds only k_bin-level entries):
//    exact deg (uncapped counts + ovf drain) -> dinv; packed capped
//    per-segment counts cnt8[n]; pre-scaled bf16 x0s rows.
//    391 blocks x 128 nodes; all count loads coalesced across threads.
__global__ __launch_bounds__(256) void k_prep(const int* __restrict__ curnx,
                                              const int* __restrict__ ovfcnt,
                                              const int* __restrict__ ovf,
                                              const float* __restrict__ x,
                                              float* __restrict__ dinv,
                                              uint2* __restrict__ cnt8,
                                              unsigned short* __restrict__ x0s) {
    __shared__ float dv[128];
    int t = threadIdx.x;
    int nb = blockIdx.x * 128;
    if (t < 128) {
        int n = nb + t;
        if (n < NNODES) {
            int c[8]; int deg = 0;
            #pragma unroll
            for (int s = 0; s < 8; ++s) { c[s] = curnx[s * NNODES + n]; deg += c[s]; }
            int novf = min(ovfcnt[0], OVFCAP);
            for (int e = 0; e < novf; ++e) {
                int v = ovf[e];
                int cc = ((((unsigned)v) >> 22) << 6) | ((v >> 16) & 63);
                if (cc == n) ++deg;
            }
            float dc = rsqrtf((float)(deg + 1));
            dinv[n] = dc; dv[t] = dc;
            unsigned lo = (unsigned)min(c[0], SCAPN) | ((unsigned)min(c[1], SCAPN) << 8)
                        | ((unsigned)min(c[2], SCAPN) << 16) | ((unsigned)min(c[3], SCAPN) << 24);
            unsigned hi = (unsigned)min(c[4], SCAPN) | ((unsigned)min(c[5], SCAPN) << 8)
                        | ((unsigned)min(c[6], SCAPN) << 16) | ((unsigned)min(c[7], SCAPN) << 24);
            cnt8[n] = make_uint2(lo, hi);
        } else dv[t] = 0.0f;
    }
    __syncthreads();
    int lane = t & 63, w = t >> 6;
    for (int i = w; i < 128; i += 4) {
        int n = nb + i;
        if (n < NNODES) {
            __hip_bfloat16 bv = __float2bfloat16(x[n * 256 + lane] * dv[i]);
            x0s[n * 64 + lane] = *(unsigned short*)&bv;
        }
    }
}

// ---------------------------------------------------------------------------
// 3) Segment rank: block = (bin, segment), 6256 blocks (24/CU). LDS returning
//    atomics rank each entry within its (segment,node) cell; stores land in
//    block-exclusive 64x20-int regions (~4 entries/line -> coalesced
//    write-back, zero cross-block sharing). Replaces the 782-block counting
//    sort and its 60 us latency floor.
__global__ __launch_bounds__(256) void k_seg(const int* __restrict__ bincur,
                                             const int* __restrict__ binned,
                                             int* __restrict__ ovfcnt,
                                             int* __restrict__ ovf,
                                             int* __restrict__ csrx) {
    __shared__ int cur[64];
    int t = threadIdx.x;
    int bin = blockIdx.x >> 3, s = blockIdx.x & 7;
    if (t < 64) cur[t] = 0;
    __syncthreads();
    int len = min(bincur[s * NBIN + bin], SCAP);
    const int* __restrict__ bb = binned + (s * NBIN + bin) * SCAP;
    for (int e = t; e < len; e += 256) {
        int v = bb[e];
        int c63 = (v >> 16) & 63;
        int rank = atomicAdd(&cur[c63], 1);
        int n = (bin << 6) | c63;
        if (rank < SCAPN) {
            csrx[(s * NNODES + n) * SCAPN + rank] = v & 0xFFFF;
        } else {
            int op = atomicAdd(ovfcnt, 1);
            if (op < OVFCAP) ovf[op] = (v & 0x3FFFFF) | (bin << 22);
        }
    }
}

// ---------------------------------------------------------------------------
// 4) Gather at the proven round-2 geometry: wave = node, lane = feature,
//    register accumulate, full occupancy (no GEMM fusion -> VGPR stays ~50).
//    Indices come from the 8 cells via a register map off wave-uniform cnt8.
__global__ __launch_bounds__(256) void k_gather(const int* __restrict__ csrx,
                                                const uint2* __restrict__ cnt8,
                                                const int* __restrict__ ovfcnt,
                                                const int* __restrict__ ovf,
                                                const unsigned short* __restrict__ x0s,
                                                const float* __restrict__ dinv,
                                                float* __restrict__ agg) {
    int t = threadIdx.x, lane = t & 63, w = t >> 6;
    int n = blockIdx.x * 4 + w;            // 12500 * 4 = 50000 exactly
    uint2 c8 = cnt8[n];
    int cl[8], pre[8];
    cl[0] = c8.x & 255; cl[1] = (c8.x >> 8) & 255; cl[2] = (c8.x >> 16) & 255; cl[3] = (c8.x >> 24) & 255;
    cl[4] = c8.y & 255; cl[5] = (c8.y >> 8) & 255; cl[6] = (c8.y >> 16) & 255; cl[7] = (c8.y >> 24) & 255;
    int acc = 0;
    #pragma unroll
    for (int s = 0; s < 8; ++s) { pre[s] = acc; acc += cl[s]; }
    int cnt = acc;
    float acc0 = bf2f(x0s[n * 64 + lane]);   // self-loop (pre-scaled)
    float acc1 = 0.0f;
    for (int base = 0; base < cnt; base += 64) {
        int m = min(cnt - base, 64);
        int ti = base + lane;
        int addr = 0;
        #pragma unroll
        for (int s = 0; s < 8; ++s) {
            if (ti >= pre[s] && ti < pre[s] + cl[s])
                addr = (s * NNODES + n) * SCAPN + (ti - pre[s]);
        }
        int idx = (lane < m) ? csrx[addr] : 0;
        int j = 0;
        for (; j + 8 <= m; j += 8) {
            int r0 = __shfl(idx, j + 0), r1 = __shfl(idx, j + 1);
            int r2 = __shfl(idx, j + 2), r3 = __shfl(idx, j + 3);
            int r4 = __shfl(idx, j + 4), r5 = __shfl(idx, j + 5);
            int r6 = __shfl(idx, j + 6), r7 = __shfl(idx, j + 7);
            float f0 = bf2f(x0s[r0 * 64 + lane]);
            float f1 = bf2f(x0s[r1 * 64 + lane]);
            float f2 = bf2f(x0s[r2 * 64 + lane]);
            float f3 = bf2f(x0s[r3 * 64 + lane]);
            float f4 = bf2f(x0s[r4 * 64 + lane]);
            float f5 = bf2f(x0s[r5 * 64 + lane]);
            float f6 = bf2f(x0s[r6 * 64 + lane]);
            float f7 = bf2f(x0s[r7 * 64 + lane]);
            acc0 += (f0 + f1) + (f2 + f3);
            acc1 += (f4 + f5) + (f6 + f7);
        }
        for (; j < m; ++j) {
            int r = __shfl(idx, j);
            acc0 += bf2f(x0s[r * 64 + lane]);
        }
    }
    // overflow drain (expected ~0 entries)
    int novf = min(ovfcnt[0], OVFCAP);
    for (int e = 0; e < novf; ++e) {
        int v = ovf[e];
        int c = ((((unsigned)v) >> 22) << 6) | ((v >> 16) & 63);
        if (c == n) acc0 += bf2f(x0s[(v & 0xFFFF) * 64 + lane]);
    }
    agg[n * 64 + lane] = (acc0 + acc1) * dinv[n];
}

// ---------------------------------------------------------------------------
// 5) per-head 64x64 linear + bias + relu, dual store (round-2, ~30 us).
__global__ __launch_bounds__(256) void k_gemm(const float* __restrict__ agg,
                                              const float* __restrict__ W,
                                              const float* __restrict__ b,
                                              float* __restrict__ out0,
                                              float* __restrict__ out1) {
    int t = threadIdx.x;
    int h = t >> 6, o = t & 63;
    float wreg[64];
    #pragma unroll
    for (int f = 0; f < 64; ++f) wreg[f] = W[h * 4096 + f * 64 + o];
    float bias = b[t];
    int n0 = blockIdx.x * 8;   // 6250 * 8 = 50000 exactly
    for (int i = 0; i < 8; ++i) {
        int n = n0 + i;
        const float* __restrict__ arow = agg + n * 64;
        float acc = bias;
        #pragma unroll
        for (int f = 0; f < 64; ++f) acc = fmaf(arow[f], wreg[f], acc);
        float v = fmaxf(acc, 0.0f);
        __builtin_nontemporal_store(v, &out0[n * 256 + t]);
        __builtin_nontemporal_store(v, &out1[n * 256 + t]);
    }
}

// ---------------------------------------------------------------------------

extern "C" void kernel_launch(void* const* d_in, const int* in_sizes, int n_in,
                              void* d_out, int out_size, void* d_ws, size_t ws_size,
                              hipStream_t stream) {
    const float* x     = (const float*)d_in[0];   // (50000, 256) f32
    const int*   edges = (const int*)d_in[1];     // (2, 1600000) int32
    const float* W     = (const float*)d_in[2];   // (4, 64, 64) f32
    const float* b     = (const float*)d_in[3];   // (4, 64) f32

    float* out0 = (float*)d_out;                   // x_cat (50000,256)
    float* out1 = out0 + (size_t)NNODES * 256;     // heads (50000,4,64) — same values

    // workspace layout
    char* ws = (char*)d_ws;
    int*            curnx  = (int*)(ws + 0);              //  1,600,000 B (8 seg x 50000)
    int*            bincur = (int*)(ws + 1600000);        //     25,024 B (8 x 782)
    int*            ovfcnt = (int*)(ws + 1625024);        //          4 B
    int*            ovf    = (int*)(ws + 1625600);        //    262,144 B
    float*          dinv   = (float*)(ws + 1887744);      //    200,000 B
    uint2*          cnt8   = (uint2*)(ws + 2088448);      //    400,000 B
    unsigned short* x0s    = (unsigned short*)(ws + 2488448);   // 6,400,000 B
    int*            binned = (int*)(ws + 8888448);        // 12,812,288 B (8 x 782 x 512)
    int*            csrx   = (int*)(ws + 21701120);       // 32,000,000 B (8 x 50000 x 20)
    float*          agg    = (float*)(ws + 53701120);     // 12,800,000 B  (total ~66.5 MB)

    hipMemsetAsync(ws, 0, 1625028, stream);   // curnx + bincur + ovfcnt
    k_bin   <<<NBBLK, 256, 0, stream>>>(edges, bincur, curnx, ovfcnt, ovf, binned);
    k_prep  <<<(NNODES + 127) / 128, 256, 0, stream>>>(curnx, ovfcnt, ovf, x, dinv, cnt8, x0s);
    k_seg   <<<NBIN * 8, 256, 0, stream>>>(bincur, binned, ovfcnt, ovf, csrx);
    k_gather<<<NNODES / 4, 256, 0, stream>>>(csrx, cnt8, ovfcnt, ovf, x0s, dinv, agg);
    k_gemm  <<<NNODES / 8, 256, 0, stream>>>(agg, W, b, out0, out1);
}

// Round 6
// 261.811 us; speedup vs baseline: 3.5306x; 1.2074x over previous
//
#include <hip/hip_runtime.h>
#include <hip/hip_bf16.h>

#define NNODES 50000
#define NEDGES 1600000
#define NBIN   782      // ceil(50000/64) destination bins of 64 nodes
#define SCAP   512      // per-(xcd,bin) segment capacity; mean 256, sigma 16
#define SCAPN  20       // per-(segment,node) cell capacity; mean 4, P(>20)~1e-8
#define OVFCAP 65536    // overflow lists (expected ~0 entries)
#define BCHUNK 2000
#define NBBLK  800      // NBBLK * BCHUNK == NEDGES

__device__ __forceinline__ float bf2f(unsigned short u) {
    union { unsigned int i; float f; } x; x.i = ((unsigned int)u) << 16; return x.f;
}

// ---------------------------------------------------------------------------
// 1) Round-2 binning, EXACT body (measured ~30 us). No per-edge degree
//    atomics (round-5 lesson: each device-scope atomic costs ~25B of
//    HBM-path traffic; 1.6M of them = +49 us). Degrees now fall out of
//    k_seg's LDS counters instead. Packs row | (c&63)<<16 | bin<<22.
__global__ __launch_bounds__(256) void k_bin(const int* __restrict__ edges,
                                             int* __restrict__ bincur,
                                             int* __restrict__ ovfcntA,
                                             int* __restrict__ ovfA,
                                             int* __restrict__ binned) {
    __shared__ int pk[BCHUNK];
    __shared__ int hist[NBIN];
    __shared__ int gbase[NBIN];
    __shared__ int lcnt[NBIN];
    int t = threadIdx.x;
    int e0 = blockIdx.x * BCHUNK;
    unsigned xcd;
    asm volatile("s_getreg_b32 %0, hwreg(HW_REG_XCC_ID)" : "=s"(xcd));
    xcd &= 7;
    for (int i = t; i < NBIN; i += 256) { hist[i] = 0; lcnt[i] = 0; }
    __syncthreads();
    for (int i = t * 4; i < BCHUNK; i += 1024) {
        int4 r4 = *(const int4*)&edges[e0 + i];
        int4 c4 = *(const int4*)&edges[NEDGES + e0 + i];
        int b0 = c4.x >> 6, b1 = c4.y >> 6, b2 = c4.z >> 6, b3 = c4.w >> 6;
        pk[i + 0] = r4.x | ((c4.x & 63) << 16) | (b0 << 22);
        pk[i + 1] = r4.y | ((c4.y & 63) << 16) | (b1 << 22);
        pk[i + 2] = r4.z | ((c4.z & 63) << 16) | (b2 << 22);
        pk[i + 3] = r4.w | ((c4.w & 63) << 16) | (b3 << 22);
        atomicAdd(&hist[b0], 1);
        atomicAdd(&hist[b1], 1);
        atomicAdd(&hist[b2], 1);
        atomicAdd(&hist[b3], 1);
    }
    __syncthreads();
    for (int i = t; i < NBIN; i += 256) {
        int h = hist[i];
        gbase[i] = (h > 0) ? atomicAdd(&bincur[xcd * NBIN + i], h) : 0;
    }
    __syncthreads();
    for (int i = t; i < BCHUNK; i += 256) {
        int v = pk[i];
        int bin = ((unsigned)v) >> 22;
        int p = gbase[bin] + atomicAdd(&lcnt[bin], 1);
        if (p < SCAP) {
            binned[(xcd * NBIN + bin) * SCAP + p] = v & 0x3FFFFF;
        } else {
            int op = atomicAdd(ovfcntA, 1);
            if (op < OVFCAP) ovfA[op] = v;   // edges that never reached binned
        }
    }
}

// ---------------------------------------------------------------------------
// 2) Segment rank: block = (bin, segment), 6256 blocks. LDS returning atomics
//    rank each entry within its (segment,node) cell; stores land in
//    block-exclusive 5 KB regions (coalesced write-back, zero cross-block
//    sharing). Final cur[64] values ARE the exact per-(segment,node) degrees
//    -> written out coalesced (replaces round-5's disastrous per-edge curnx
//    atomics). Rank >= SCAPN spills to list B (already counted in cur).
__global__ __launch_bounds__(256) void k_seg(const int* __restrict__ bincur,
                                             const int* __restrict__ binned,
                                             int* __restrict__ ovfcntB,
                                             int* __restrict__ ovfB,
                                             int* __restrict__ csrx,
                                             int* __restrict__ cntseg) {
    __shared__ int cur[64];
    int t = threadIdx.x;
    int bin = blockIdx.x >> 3, s = blockIdx.x & 7;
    if (t < 64) cur[t] = 0;
    __syncthreads();
    int len = min(bincur[s * NBIN + bin], SCAP);
    const int* __restrict__ bb = binned + (s * NBIN + bin) * SCAP;
    for (int e = t; e < len; e += 256) {
        int v = bb[e];
        int c63 = (v >> 16) & 63;
        int rank = atomicAdd(&cur[c63], 1);
        int n = (bin << 6) | c63;
        if (rank < SCAPN) {
            csrx[(s * NNODES + n) * SCAPN + rank] = v & 0xFFFF;
        } else {
            int op = atomicAdd(ovfcntB, 1);
            if (op < OVFCAP) ovfB[op] = v;   // counted in cur; drain in gather only
        }
    }
    __syncthreads();
    if (t < 64) {
        int n = (bin << 6) | t;
        if (n < NNODES) cntseg[s * NNODES + n] = cur[t];
    }
}

// ---------------------------------------------------------------------------
// 3) Prep (after k_seg): deg = sum of 8 exact segment counts + list-A matches
//    -> dinv; packed capped per-segment counts cnt8; pre-scaled bf16 x0s.
//    391 blocks x 128 nodes; count loads coalesced.
__global__ __launch_bounds__(256) void k_prep(const int* __restrict__ cntseg,
                                              const int* __restrict__ ovfcntA,
                                              const int* __restrict__ ovfA,
                                              const float* __restrict__ x,
                                              float* __restrict__ dinv,
                                              uint2* __restrict__ cnt8,
                                              unsigned short* __restrict__ x0s) {
    __shared__ float dv[128];
    int t = threadIdx.x;
    int nb = blockIdx.x * 128;
    if (t < 128) {
        int n = nb + t;
        if (n < NNODES) {
            int c[8]; int deg = 0;
            #pragma unroll
            for (int s = 0; s < 8; ++s) { c[s] = cntseg[s * NNODES + n]; deg += c[s]; }
            int novf = min(ovfcntA[0], OVFCAP);
            for (int e = 0; e < novf; ++e) {
                int v = ovfA[e];
                int cc = ((((unsigned)v) >> 22) << 6) | ((v >> 16) & 63);
                if (cc == n) ++deg;
            }
            float dc = rsqrtf((float)(deg + 1));
            dinv[n] = dc; dv[t] = dc;
            unsigned lo = (unsigned)min(c[0], SCAPN) | ((unsigned)min(c[1], SCAPN) << 8)
                        | ((unsigned)min(c[2], SCAPN) << 16) | ((unsigned)min(c[3], SCAPN) << 24);
            unsigned hi = (unsigned)min(c[4], SCAPN) | ((unsigned)min(c[5], SCAPN) << 8)
                        | ((unsigned)min(c[6], SCAPN) << 16) | ((unsigned)min(c[7], SCAPN) << 24);
            cnt8[n] = make_uint2(lo, hi);
        } else dv[t] = 0.0f;
    }
    __syncthreads();
    int lane = t & 63, w = t >> 6;
    for (int i = w; i < 128; i += 4) {
        int n = nb + i;
        if (n < NNODES) {
            __hip_bfloat16 bv = __float2bfloat16(x[n * 256 + lane] * dv[i]);
            x0s[n * 64 + lane] = *(unsigned short*)&bv;
        }
    }
}

// ---------------------------------------------------------------------------
// 4) Gather at the proven round-2 geometry: wave = node, lane = feature,
//    register accumulate, full occupancy. Indices from the 8 cells via a
//    register map off wave-uniform cnt8. Drains both overflow lists.
__global__ __launch_bounds__(256) void k_gather(const int* __restrict__ csrx,
                                                const uint2* __restrict__ cnt8,
                                                const int* __restrict__ ovfcntA,
                                                const int* __restrict__ ovfA,
                                                const int* __restrict__ ovfcntB,
                                                const int* __restrict__ ovfB,
                                                const unsigned short* __restrict__ x0s,
                                                const float* __restrict__ dinv,
                                                float* __restrict__ agg) {
    int t = threadIdx.x, lane = t & 63, w = t >> 6;
    int n = blockIdx.x * 4 + w;            // 12500 * 4 = 50000 exactly
    uint2 c8 = cnt8[n];
    int cl[8], pre[8];
    cl[0] = c8.x & 255; cl[1] = (c8.x >> 8) & 255; cl[2] = (c8.x >> 16) & 255; cl[3] = (c8.x >> 24) & 255;
    cl[4] = c8.y & 255; cl[5] = (c8.y >> 8) & 255; cl[6] = (c8.y >> 16) & 255; cl[7] = (c8.y >> 24) & 255;
    int acc = 0;
    #pragma unroll
    for (int s = 0; s < 8; ++s) { pre[s] = acc; acc += cl[s]; }
    int cnt = acc;
    float acc0 = bf2f(x0s[n * 64 + lane]);   // self-loop (pre-scaled)
    float acc1 = 0.0f;
    for (int base = 0; base < cnt; base += 64) {
        int m = min(cnt - base, 64);
        int ti = base + lane;
        int addr = 0;
        #pragma unroll
        for (int s = 0; s < 8; ++s) {
            if (ti >= pre[s] && ti < pre[s] + cl[s])
                addr = (s * NNODES + n) * SCAPN + (ti - pre[s]);
        }
        int idx = (lane < m) ? csrx[addr] : 0;
        int j = 0;
        for (; j + 8 <= m; j += 8) {
            int r0 = __shfl(idx, j + 0), r1 = __shfl(idx, j + 1);
            int r2 = __shfl(idx, j + 2), r3 = __shfl(idx, j + 3);
            int r4 = __shfl(idx, j + 4), r5 = __shfl(idx, j + 5);
            int r6 = __shfl(idx, j + 6), r7 = __shfl(idx, j + 7);
            float f0 = bf2f(x0s[r0 * 64 + lane]);
            float f1 = bf2f(x0s[r1 * 64 + lane]);
            float f2 = bf2f(x0s[r2 * 64 + lane]);
            float f3 = bf2f(x0s[r3 * 64 + lane]);
            float f4 = bf2f(x0s[r4 * 64 + lane]);
            float f5 = bf2f(x0s[r5 * 64 + lane]);
            float f6 = bf2f(x0s[r6 * 64 + lane]);
            float f7 = bf2f(x0s[r7 * 64 + lane]);
            acc0 += (f0 + f1) + (f2 + f3);
            acc1 += (f4 + f5) + (f6 + f7);
        }
        for (; j < m; ++j) {
            int r = __shfl(idx, j);
            acc0 += bf2f(x0s[r * 64 + lane]);
        }
    }
    // overflow drains (expected empty)
    int novfA = min(ovfcntA[0], OVFCAP);
    for (int e = 0; e < novfA; ++e) {
        int v = ovfA[e];
        int c = ((((unsigned)v) >> 22) << 6) | ((v >> 16) & 63);
        if (c == n) acc0 += bf2f(x0s[(v & 0xFFFF) * 64 + lane]);
    }
    int novfB = min(ovfcntB[0], OVFCAP);
    for (int e = 0; e < novfB; ++e) {
        int v = ovfB[e];
        int c = ((((unsigned)v) >> 22) << 6) | ((v >> 16) & 63);
        if (c == n) acc0 += bf2f(x0s[(v & 0xFFFF) * 64 + lane]);
    }
    agg[n * 64 + lane] = (acc0 + acc1) * dinv[n];
}

// ---------------------------------------------------------------------------
// 5) per-head 64x64 linear + bias + relu, dual store (round-2, ~30 us).
__global__ __launch_bounds__(256) void k_gemm(const float* __restrict__ agg,
                                              const float* __restrict__ W,
                                              const float* __restrict__ b,
                                              float* __restrict__ out0,
                                              float* __restrict__ out1) {
    int t = threadIdx.x;
    int h = t >> 6, o = t & 63;
    float wreg[64];
    #pragma unroll
    for (int f = 0; f < 64; ++f) wreg[f] = W[h * 4096 + f * 64 + o];
    float bias = b[t];
    int n0 = blockIdx.x * 8;   // 6250 * 8 = 50000 exactly
    for (int i = 0; i < 8; ++i) {
        int n = n0 + i;
        const float* __restrict__ arow = agg + n * 64;
        float acc = bias;
        #pragma unroll
        for (int f = 0; f < 64; ++f) acc = fmaf(arow[f], wreg[f], acc);
        float v = fmaxf(acc, 0.0f);
        __builtin_nontemporal_store(v, &out0[n * 256 + t]);
        __builtin_nontemporal_store(v, &out1[n * 256 + t]);
    }
}

// ---------------------------------------------------------------------------

extern "C" void kernel_launch(void* const* d_in, const int* in_sizes, int n_in,
                              void* d_out, int out_size, void* d_ws, size_t ws_size,
                              hipStream_t stream) {
    const float* x     = (const float*)d_in[0];   // (50000, 256) f32
    const int*   edges = (const int*)d_in[1];     // (2, 1600000) int32
    const float* W     = (const float*)d_in[2];   // (4, 64, 64) f32
    const float* b     = (const float*)d_in[3];   // (4, 64) f32

    float* out0 = (float*)d_out;                   // x_cat (50000,256)
    float* out1 = out0 + (size_t)NNODES * 256;     // heads (50000,4,64) — same values

    // workspace layout
    char* ws = (char*)d_ws;
    int*            bincur  = (int*)(ws + 0);              //     25,024 B (8 x 782)
    int*            ovfcntA = (int*)(ws + 25024);          //          4 B
    int*            ovfcntB = (int*)(ws + 25028);          //          4 B
    int*            ovfA    = (int*)(ws + 25600);          //    262,144 B
    int*            ovfB    = (int*)(ws + 287744);         //    262,144 B
    float*          dinv    = (float*)(ws + 549888);       //    200,000 B
    uint2*          cnt8    = (uint2*)(ws + 750080);       //    400,000 B
    unsigned short* x0s     = (unsigned short*)(ws + 1150080);  // 6,400,000 B
    int*            cntseg  = (int*)(ws + 7550080);        //  1,600,000 B (8 x 50000)
    int*            binned  = (int*)(ws + 9150080);        // 12,812,288 B (8 x 782 x 512)
    int*            csrx    = (int*)(ws + 21962368);       // 32,000,000 B (8 x 50000 x 20)
    float*          agg     = (float*)(ws + 53962368);     // 12,800,000 B  (total ~66.8 MB)

    hipMemsetAsync(ws, 0, 25032, stream);   // bincur + ovfcntA + ovfcntB
    k_bin   <<<NBBLK, 256, 0, stream>>>(edges, bincur, ovfcntA, ovfA, binned);
    k_seg   <<<NBIN * 8, 256, 0, stream>>>(bincur, binned, ovfcntB, ovfB, csrx, cntseg);
    k_prep  <<<(NNODES + 127) / 128, 256, 0, stream>>>(cntseg, ovfcntA, ovfA, x, dinv, cnt8, x0s);
    k_gather<<<NNODES / 4, 256, 0, stream>>>(csrx, cnt8, ovfcntA, ovfA, ovfcntB, ovfB, x0s, dinv, agg);
    k_gemm  <<<NNODES / 8, 256, 0, stream>>>(agg, W, b, out0, out1);
}

// Round 7
// 244.547 us; speedup vs baseline: 3.7799x; 1.0706x over previous
//
#include <hip/hip_runtime.h>
#include <hip/hip_bf16.h>

#define NNODES 50000
#define NEDGES 1600000
#define NBIN2  1564     // ceil(50000/32) destination bins of 32 nodes
#define CAPB2  1440     // per-bin total capacity; mean 1024, sigma ~32 (+13 sigma)
#define SCAP   320      // per-(xcd,bin) segment capacity; mean 128, sigma ~11
#define OVFCAP 65536    // overflow list (expected 0 entries)
#define BCHUNK 2000
#define NBBLK  800      // NBBLK * BCHUNK == NEDGES

__device__ __forceinline__ float bf2f(unsigned short u) {
    union { unsigned int i; float f; } x; x.i = ((unsigned int)u) << 16; return x.f;
}

// ---------------------------------------------------------------------------
// 1) Round-2 binning body, 32-node bins. Packs r | (c&31)<<16 | bin<<21
//    (16+5+11 = 32 bits exactly). Per-XCD sub-segments -> no cross-XCD
//    line ping-pong (round-2 lesson); no per-edge global atomics
//    (round-5 lesson).
__global__ __launch_bounds__(256) void k_bin(const int* __restrict__ edges,
                                             int* __restrict__ bincur,
                                             int* __restrict__ ovfcnt,
                                             int* __restrict__ ovf,
                                             int* __restrict__ binned) {
    __shared__ int pk[BCHUNK];
    __shared__ int hist[NBIN2];
    __shared__ int gbase[NBIN2];
    __shared__ int lcnt[NBIN2];
    int t = threadIdx.x;
    int e0 = blockIdx.x * BCHUNK;
    unsigned xcd;
    asm volatile("s_getreg_b32 %0, hwreg(HW_REG_XCC_ID)" : "=s"(xcd));
    xcd &= 7;
    for (int i = t; i < NBIN2; i += 256) { hist[i] = 0; lcnt[i] = 0; }
    __syncthreads();
    for (int i = t * 4; i < BCHUNK; i += 1024) {
        int4 r4 = *(const int4*)&edges[e0 + i];
        int4 c4 = *(const int4*)&edges[NEDGES + e0 + i];
        int b0 = c4.x >> 5, b1 = c4.y >> 5, b2 = c4.z >> 5, b3 = c4.w >> 5;
        pk[i + 0] = r4.x | ((c4.x & 31) << 16) | (b0 << 21);
        pk[i + 1] = r4.y | ((c4.y & 31) << 16) | (b1 << 21);
        pk[i + 2] = r4.z | ((c4.z & 31) << 16) | (b2 << 21);
        pk[i + 3] = r4.w | ((c4.w & 31) << 16) | (b3 << 21);
        atomicAdd(&hist[b0], 1);
        atomicAdd(&hist[b1], 1);
        atomicAdd(&hist[b2], 1);
        atomicAdd(&hist[b3], 1);
    }
    __syncthreads();
    for (int i = t; i < NBIN2; i += 256) {
        int h = hist[i];
        gbase[i] = (h > 0) ? atomicAdd(&bincur[xcd * NBIN2 + i], h) : 0;
    }
    __syncthreads();
    for (int i = t; i < BCHUNK; i += 256) {
        int v = pk[i];
        int bin = ((unsigned)v) >> 21;
        int p = gbase[bin] + atomicAdd(&lcnt[bin], 1);
        if (p < SCAP) {
            binned[(xcd * NBIN2 + bin) * SCAP + p] = v;
        } else {
            int op = atomicAdd(ovfcnt, 1);
            if (op < OVFCAP) ovf[op] = v;
        }
    }
}

// ---------------------------------------------------------------------------
// 2) Per-bin LDS counting sort (32-node bins: half the serial depth, 2x the
//    blocks/CU of round-2's 64-node version). Segments processed two at a
//    time so both 128-thread halves stay busy. x row loads hoisted to kernel
//    entry so their HBM latency hides under the whole sort. Fused outputs:
//    dinv, rowptr/cntn, pre-scaled bf16 x0s, node-contiguous csr.
__global__ __launch_bounds__(256) void k_sortbin(const int* __restrict__ bincur,
                                                 const int* __restrict__ binned,
                                                 const int* __restrict__ ovfcnt,
                                                 const int* __restrict__ ovf,
                                                 const float* __restrict__ x,
                                                 int* __restrict__ rowptr,
                                                 int* __restrict__ cntn,
                                                 float* __restrict__ dinv,
                                                 unsigned short* __restrict__ x0s,
                                                 int* __restrict__ csr) {
    __shared__ int h[32];
    __shared__ int off[32];
    __shared__ int cur[32];
    __shared__ float dv[32];
    __shared__ int slen[8];
    __shared__ int stage[CAPB2];
    int t = threadIdx.x, bin = blockIdx.x;
    int wave = t >> 6, lane = t & 63;
    int n0 = bin * 32;
    // hoisted x loads (independent of everything below)
    float xv[8];
    #pragma unroll
    for (int k = 0; k < 8; ++k) {
        int n = n0 + wave + 4 * k;
        xv[k] = (n < NNODES) ? x[n * 256 + lane] : 0.0f;
    }
    if (t < 32) h[t] = 0;
    if (t < 8) slen[t] = min(bincur[t * NBIN2 + bin], SCAP);
    __syncthreads();
    int novf = ovfcnt[0];
    // histogram: two segments concurrently (t>>7 selects the segment)
    for (int sp = 0; sp < 8; sp += 2) {
        int s = sp + (t >> 7);
        int tl = t & 127;
        int len = slen[s];
        const int* __restrict__ bb = binned + (s * NBIN2 + bin) * SCAP;
        for (int e = tl; e < len; e += 128)
            atomicAdd(&h[(bb[e] >> 16) & 31], 1);
    }
    for (int e = t; e < novf; e += 256) {
        int v = ovf[e];
        if (((unsigned)v >> 21) == (unsigned)bin) atomicAdd(&h[(v >> 16) & 31], 1);
    }
    __syncthreads();
    if (t < 32) {
        int v = h[t];
        int inc = v;
        #pragma unroll
        for (int d = 1; d < 32; d <<= 1) {
            int u = __shfl_up(inc, d);
            if (lane >= d) inc += u;
        }
        int ex = inc - v;
        off[t] = ex;
        cur[t] = ex;
        float dc = rsqrtf((float)(v + 1));
        dv[t] = dc;
        int n = n0 + t;
        if (n < NNODES) {
            dinv[n] = dc;
            rowptr[n] = bin * CAPB2 + ex;
            cntn[n] = v;
        }
    }
    __syncthreads();
    // placement: same two-segment concurrency
    for (int sp = 0; sp < 8; sp += 2) {
        int s = sp + (t >> 7);
        int tl = t & 127;
        int len = slen[s];
        const int* __restrict__ bb = binned + (s * NBIN2 + bin) * SCAP;
        for (int e = tl; e < len; e += 128) {
            int v = bb[e];
            int p = atomicAdd(&cur[(v >> 16) & 31], 1);
            if (p < CAPB2) stage[p] = v & 0xFFFF;
        }
    }
    for (int e = t; e < novf; e += 256) {
        int v = ovf[e];
        if (((unsigned)v >> 21) == (unsigned)bin) {
            int p = atomicAdd(&cur[(v >> 16) & 31], 1);
            if (p < CAPB2) stage[p] = v & 0xFFFF;
        }
    }
    __syncthreads();
    int total = min(off[31] + h[31], CAPB2);
    for (int e = t; e < total; e += 256)
        csr[bin * CAPB2 + e] = stage[e];
    // pre-scaled bf16 rows from the hoisted registers
    #pragma unroll
    for (int k = 0; k < 8; ++k) {
        int i = wave + 4 * k;
        int n = n0 + i;
        if (n < NNODES) {
            __hip_bfloat16 v = __float2bfloat16(xv[k] * dv[i]);
            x0s[n * 64 + lane] = *(unsigned short*)&v;
        }
    }
}

// ---------------------------------------------------------------------------
// 3) Per-node gather (round-2 proven geometry, unchanged): wave = node,
//    lane = feature, register accumulate, 50K waves, full occupancy.
__global__ __launch_bounds__(256) void k_gather(const unsigned short* __restrict__ x0s,
                                                const int* __restrict__ rowptr,
                                                const int* __restrict__ cntn,
                                                const float* __restrict__ dinv,
                                                const int* __restrict__ csr,
                                                float* __restrict__ agg) {
    int wave = threadIdx.x >> 6, lane = threadIdx.x & 63;
    int n = blockIdx.x * 4 + wave;          // 12500 * 4 = 50000 exactly
    int start = rowptr[n], len = cntn[n];
    float acc0 = bf2f(x0s[n * 64 + lane]);  // self-loop (pre-scaled)
    float acc1 = 0.0f;
    for (int base = 0; base < len; base += 64) {
        int m = min(len - base, 64);
        int idx = (lane < m) ? csr[start + base + lane] : 0;  // one coalesced load
        int j = 0;
        for (; j + 8 <= m; j += 8) {
            int r0 = __shfl(idx, j + 0), r1 = __shfl(idx, j + 1);
            int r2 = __shfl(idx, j + 2), r3 = __shfl(idx, j + 3);
            int r4 = __shfl(idx, j + 4), r5 = __shfl(idx, j + 5);
            int r6 = __shfl(idx, j + 6), r7 = __shfl(idx, j + 7);
            float f0 = bf2f(x0s[r0 * 64 + lane]);
            float f1 = bf2f(x0s[r1 * 64 + lane]);
            float f2 = bf2f(x0s[r2 * 64 + lane]);
            float f3 = bf2f(x0s[r3 * 64 + lane]);
            float f4 = bf2f(x0s[r4 * 64 + lane]);
            float f5 = bf2f(x0s[r5 * 64 + lane]);
            float f6 = bf2f(x0s[r6 * 64 + lane]);
            float f7 = bf2f(x0s[r7 * 64 + lane]);
            acc0 += (f0 + f1) + (f2 + f3);
            acc1 += (f4 + f5) + (f6 + f7);
        }
        for (; j < m; ++j) {
            int r = __shfl(idx, j);
            acc0 += bf2f(x0s[r * 64 + lane]);
        }
    }
    agg[n * 64 + lane] = (acc0 + acc1) * dinv[n];
}

// ---------------------------------------------------------------------------
// 4) per-head 64x64 linear + bias + relu, dual store. 2000 blocks x 25 nodes
//    (was 6250 x 8): full-W-per-block L2 traffic 400 MB -> 128 MB while
//    keeping 8000 waves for store BW.
__global__ __launch_bounds__(256) void k_gemm(const float* __restrict__ agg,
                                              const float* __restrict__ W,
                                              const float* __restrict__ b,
                                              float* __restrict__ out0,
                                              float* __restrict__ out1) {
    int t = threadIdx.x;
    int h = t >> 6, o = t & 63;
    float wreg[64];
    #pragma unroll
    for (int f = 0; f < 64; ++f) wreg[f] = W[h * 4096 + f * 64 + o];
    float bias = b[t];
    int n0 = blockIdx.x * 25;   // 2000 * 25 = 50000 exactly
    for (int i = 0; i < 25; ++i) {
        int n = n0 + i;
        const float* __restrict__ arow = agg + n * 64;   // block-uniform address
        float acc = bias;
        #pragma unroll
        for (int f = 0; f < 64; ++f) acc = fmaf(arow[f], wreg[f], acc);
        float v = fmaxf(acc, 0.0f);
        __builtin_nontemporal_store(v, &out0[n * 256 + t]);
        __builtin_nontemporal_store(v, &out1[n * 256 + t]);
    }
}

// ---------------------------------------------------------------------------

extern "C" void kernel_launch(void* const* d_in, const int* in_sizes, int n_in,
                              void* d_out, int out_size, void* d_ws, size_t ws_size,
                              hipStream_t stream) {
    const float* x     = (const float*)d_in[0];   // (50000, 256) f32
    const int*   edges = (const int*)d_in[1];     // (2, 1600000) int32
    const float* W     = (const float*)d_in[2];   // (4, 64, 64) f32
    const float* b     = (const float*)d_in[3];   // (4, 64) f32

    float* out0 = (float*)d_out;                   // x_cat (50000,256)
    float* out1 = out0 + (size_t)NNODES * 256;     // heads (50000,4,64) — same values

    // workspace layout (512B-aligned sections)
    char* ws = (char*)d_ws;
    int*            bincur = (int*)(ws + 0);              //     50,048 B (8 x 1564)
    int*            ovfcnt = (int*)(ws + 50176);          //          4 B
    int*            ovf    = (int*)(ws + 50688);          //    262,144 B
    float*          dinv   = (float*)(ws + 312832);       //    200,000 B
    int*            rowptr = (int*)(ws + 513024);         //    200,000 B
    int*            cntn   = (int*)(ws + 713216);         //    200,000 B
    int*            binned = (int*)(ws + 913408);         // 16,015,360 B (8 x 1564 x 320)
    int*            csr    = (int*)(ws + 16928768);       //  9,008,640 B (1564 x 1440)
    unsigned short* x0s    = (unsigned short*)(ws + 25937408);  // 6,400,000 B
    float*          agg    = (float*)(ws + 32337408);     // 12,800,000 B  (total ~45.1 MB)

    hipMemsetAsync(ws, 0, 50180, stream);   // bincur + ovfcnt
    k_bin    <<<NBBLK, 256, 0, stream>>>(edges, bincur, ovfcnt, ovf, binned);
    k_sortbin<<<NBIN2, 256, 0, stream>>>(bincur, binned, ovfcnt, ovf, x, rowptr, cntn, dinv, x0s, csr);
    k_gather <<<NNODES / 4, 256, 0, stream>>>(x0s, rowptr, cntn, dinv, csr, agg);
    k_gemm   <<<2000, 256, 0, stream>>>(agg, W, b, out0, out1);
}